// Round 3
// baseline (535.312 us; speedup 1.0000x reference)
//
#include <hip/hip_runtime.h>
#include <math.h>

// Problem constants (match reference)
#define CUTOFF_F 10.0f
#define PI_OVER_CUTOFF 0.31415926535897931f  // pi/10
#define KID 32   // per-node bucket capacity (compact ids / edge ids)

// ===========================================================================
// Mode 6 pass 1: stream edges, fold cutoff coeff into a packed 16-float row
// per VALID edge, written SEQUENTIALLY at a wave-compacted index (one global
// atomic per wave). Per-node ticket writes a 4B compact-id into the bucket
// (cache-resident). Random-write traffic ~ bucket only; big write is stream.
// Overflow (slot>=KID or cid>=C) -> fp32 atomics into aggr (rare/never).
// ===========================================================================
__global__ __launch_bounds__(256) void pack_compact(
    const float* __restrict__ gds,
    const int* __restrict__ eidx,
    const float* __restrict__ edge_sca,
    const float* __restrict__ edge_vec,
    int* __restrict__ count,    // [N] per-node tickets (zeroed)
    int* __restrict__ gslot,    // [1] global compact counter (zeroed)
    int* __restrict__ bucket,   // [N*KID] compact ids
    float* __restrict__ packed, // [C*16] c-folded features
    float* __restrict__ aggr,   // [N*16] overflow accumulator (zeroed)
    int E, int C)
{
    int e = blockIdx.x * 256 + threadIdx.x;
    bool keep = false;
    float d = 0.0f;
    if (e < E) {
        d = gds[e];
        keep = (d >= 0.0f && d <= CUTOFF_F);  // coeff==0 outside -> drop
    }

    unsigned long long act = __ballot(keep);
    if (act == 0ull) return;

    int lane = threadIdx.x & 63;
    int leader = __ffsll((unsigned long long)act) - 1;
    int nact = __popcll(act);
    int prefix = __popcll(act & ((1ull << lane) - 1ull));

    int base = 0;
    if (lane == leader) base = atomicAdd(gslot, nact);
    base = __shfl(base, leader);

    if (!keep) return;

    int cid = base + prefix;
    int src = eidx[e];
    float c = 0.5f * (__cosf(d * PI_OVER_CUTOFF) + 1.0f);
    const float* es = edge_sca + (size_t)e * 6;
    const float* ev = edge_vec + (size_t)e * 9;

    float f[16];
#pragma unroll
    for (int i = 0; i < 6; ++i) f[i] = c * es[i];
    f[6] = c;
#pragma unroll
    for (int i = 0; i < 9; ++i) f[7 + i] = c * ev[i];

    bool ok = (cid < C);
    int slot = KID;
    if (ok) slot = atomicAdd(&count[src], 1);

    if (ok && slot < KID) {
        bucket[(size_t)src * KID + slot] = cid;
        float4* pr = (float4*)(packed + (size_t)cid * 16);
        pr[0] = make_float4(f[0],  f[1],  f[2],  f[3]);
        pr[1] = make_float4(f[4],  f[5],  f[6],  f[7]);
        pr[2] = make_float4(f[8],  f[9],  f[10], f[11]);
        pr[3] = make_float4(f[12], f[13], f[14], f[15]);
    } else {
        float* bb = aggr + (size_t)src * 16;
#pragma unroll
        for (int i = 0; i < 16; ++i) atomicAdd(bb + i, f[i]);
    }
}

// ===========================================================================
// Mode 4 fallback: scatter edge IDS only, gather raw features in node_fused.
// ===========================================================================
__global__ __launch_bounds__(256) void fill_ids(
    const float* __restrict__ gds,
    const int* __restrict__ eidx,
    const float* __restrict__ edge_sca,
    const float* __restrict__ edge_vec,
    int* __restrict__ count,
    int* __restrict__ bucket,   // [N*KID] edge ids
    float* __restrict__ aggr,   // [N*16] overflow accumulator (zeroed)
    int E)
{
    int e = blockIdx.x * blockDim.x + threadIdx.x;
    if (e >= E) return;

    float d = gds[e];
    if (d > CUTOFF_F || d < 0.0f) return;

    int src = eidx[e];
    int slot = atomicAdd(&count[src], 1);
    if (slot < KID) {
        bucket[(size_t)src * KID + slot] = e;
    } else {
        float c = 0.5f * (__cosf(d * PI_OVER_CUTOFF) + 1.0f);
        const float* es = edge_sca + (size_t)e * 6;
        const float* ev = edge_vec + (size_t)e * 9;
        float* base = aggr + (size_t)src * 16;
#pragma unroll
        for (int i = 0; i < 6; ++i) atomicAdd(base + i, c * es[i]);
        atomicAdd(base + 6, c);
#pragma unroll
        for (int i = 0; i < 9; ++i) atomicAdd(base + 7 + i, c * ev[i]);
    }
}

// ===========================================================================
// Mode 0 fallback: pure fp32 atomic aggregation (tiny workspace)
// ===========================================================================
__global__ __launch_bounds__(256) void edge_aggregate(
    const float* __restrict__ edge_sca, const float* __restrict__ edge_vec,
    const float* __restrict__ gds, const int* __restrict__ eidx,
    float* __restrict__ aggr, int E)
{
    int e = blockIdx.x * blockDim.x + threadIdx.x;
    if (e >= E) return;
    int src = eidx[e];
    float d = gds[e];
    float coeff = 0.0f;
    if (d >= 0.0f && d <= CUTOFF_F)
        coeff = 0.5f * (__cosf(d * PI_OVER_CUTOFF) + 1.0f);
    float* base = aggr + (size_t)src * 16;
    const float* es = edge_sca + (size_t)e * 6;
    const float* ev = edge_vec + (size_t)e * 9;
#pragma unroll
    for (int c = 0; c < 6; ++c) atomicAdd(base + c, coeff * es[c]);
    atomicAdd(base + 6, coeff);
#pragma unroll
    for (int k = 0; k < 9; ++k) atomicAdd(base + 7 + k, coeff * ev[k]);
}

// ===========================================================================
// Fused node kernel. mode: 6 = packed-row gather via compact-id bucket,
// 4 = id-bucket raw-feature gather, 0 = aggr only.
// 16 lanes per node, 16 nodes per 256-block.
// ===========================================================================
__global__ __launch_bounds__(256) void node_fused(
    const float* __restrict__ node_sca,
    const float* __restrict__ node_vec,
    const float* __restrict__ edge_sca,
    const float* __restrict__ edge_vec,
    const float* __restrict__ gds,
    const int* __restrict__ count,
    const int* __restrict__ bucket,      // mode 6: compact ids; mode 4: edge ids
    const float* __restrict__ packed,    // mode 6: packed rows
    const float* __restrict__ aggr,      // mode 0 / overflow
    const float* __restrict__ W_nss, const float* __restrict__ b_nss,
    const float* __restrict__ W_ess, const float* __restrict__ b_ess,
    const float* __restrict__ W_nsv, const float* __restrict__ b_nsv,
    const float* __restrict__ W_esv, const float* __restrict__ b_esv,
    const float* __restrict__ W_nvv, const float* __restrict__ W_evv,
    const float* __restrict__ W_lv,  const float* __restrict__ W_lv2,
    const float* __restrict__ W_ls,
    const float* __restrict__ W_gate, const float* __restrict__ b_gate,
    const float* __restrict__ W_dir,
    float* __restrict__ out,
    int N, int mode)
{
    // ---- weights in LDS ----
    __shared__ float sW_nss[64],  sb_nss[16];
    __shared__ float sW_ess[96],  sb_ess[16];
    __shared__ float sW_nsv[64],  sb_nsv[16];
    __shared__ float sW_esv[96],  sb_esv[16];
    __shared__ float sW_nvv[48],  sW_evv[48];
    __shared__ float sW_lv[256],  sW_lv2[256];
    __shared__ float sW_ls[512];
    __shared__ float sW_gate[256], sb_gate[16];
    __shared__ float sW_dir[256];

    // ---- per-node scratch (odd node-strides -> no bank conflicts) ----
    __shared__ float s_in  [16 * 33];
    __shared__ float s_avec[16 * 49];
    __shared__ float s_cat [16 * 33];
    __shared__ float s_vint[16 * 49];   // also overlays id staging
    __shared__ float s_osca[16 * 17];
    __shared__ float s_ovec[16 * 49];   // also overlays mode-4 coeff staging

    // staging overlays (used strictly before s_vint/s_ovec are written)
    int*   s_eid = (int*)s_vint;        // [KID*17] = 544 ints <= 784
    float* s_ec  = s_ovec;              // [KID*17] = 544 floats <= 784

    const int t = threadIdx.x;
    {
        for (int i = t; i < 64;  i += 256) { sW_nss[i] = W_nss[i]; sW_nsv[i] = W_nsv[i]; }
        for (int i = t; i < 96;  i += 256) { sW_ess[i] = W_ess[i]; sW_esv[i] = W_esv[i]; }
        for (int i = t; i < 48;  i += 256) { sW_nvv[i] = W_nvv[i]; sW_evv[i] = W_evv[i]; }
        for (int i = t; i < 256; i += 256) {
            sW_lv[i]   = W_lv[i];
            sW_lv2[i]  = W_lv2[i];
            sW_gate[i] = W_gate[i];
            sW_dir[i]  = W_dir[i];
        }
        for (int i = t; i < 512; i += 256) sW_ls[i] = W_ls[i];
        if (t < 16) {
            sb_nss[t]  = b_nss[t];
            sb_ess[t]  = b_ess[t];
            sb_nsv[t]  = b_nsv[t];
            sb_esv[t]  = b_esv[t];
            sb_gate[t] = b_gate[t];
        }
    }

    const int slot = t >> 4;
    const int o    = t & 15;
    const int n    = blockIdx.x * 16 + slot;
    const bool valid = (n < N);

    if (valid) {
        if (o < 4) s_in[slot * 33 + o]     = node_sca[(size_t)n * 4 + o];
        if (o < 9) s_in[slot * 33 + 4 + o] = node_vec[(size_t)n * 9 + o];
    }

    if (mode == 6) {
        int cnt = 0;
        if (valid) {
            cnt = count[n];
            if (cnt > KID) cnt = KID;
            const int* bk = bucket + (size_t)n * KID;
            for (int s = o; s < cnt; s += 16)
                s_eid[s * 17 + slot] = bk[s];   // coalesced 64B per group
        }
        __syncthreads();
        if (valid) {
            float a0 = 0.f, a1 = 0.f, a2 = 0.f, a3 = 0.f;
            int s = 0;
            for (; s + 3 < cnt; s += 4) {
                int c0 = s_eid[(s + 0) * 17 + slot];
                int c1 = s_eid[(s + 1) * 17 + slot];
                int c2 = s_eid[(s + 2) * 17 + slot];
                int c3 = s_eid[(s + 3) * 17 + slot];
                a0 += packed[(size_t)c0 * 16 + o];   // 4 independent 64B
                a1 += packed[(size_t)c1 * 16 + o];   // sector reads in flight
                a2 += packed[(size_t)c2 * 16 + o];
                a3 += packed[(size_t)c3 * 16 + o];
            }
            for (; s < cnt; ++s)
                a0 += packed[(size_t)s_eid[s * 17 + slot] * 16 + o];
            a1 += aggr[(size_t)n * 16 + o];   // overflow (zero if none)
            s_in[slot * 33 + 13 + o] = (a0 + a1) + (a2 + a3);
        }
    } else if (mode == 4) {
        int cnt = 0;
        if (valid) {
            cnt = count[n];
            if (cnt > KID) cnt = KID;
            const int* bk = bucket + (size_t)n * KID;
            for (int s = o; s < cnt; s += 16) {
                int e = bk[s];
                float d = gds[e];
                s_eid[s * 17 + slot] = e;
                s_ec [s * 17 + slot] = 0.5f * (__cosf(d * PI_OVER_CUTOFF) + 1.0f);
            }
        }
        __syncthreads();
        if (valid) {
            float acc = aggr[(size_t)n * 16 + o];
            const float* fsrc = (o < 6) ? edge_sca : edge_vec;
            const int    st   = (o < 6) ? 6 : 9;
            const int    off  = (o < 6) ? o : (o - 7);
            for (int s = 0; s < cnt; ++s) {
                int   e = s_eid[s * 17 + slot];
                float c = s_ec [s * 17 + slot];
                float f = (o == 6) ? 1.0f : fsrc[(size_t)e * st + off];
                acc += c * f;
            }
            s_in[slot * 33 + 13 + o] = acc;
        }
    } else {
        if (valid) s_in[slot * 33 + 13 + o] = aggr[(size_t)n * 16 + o];
    }
    __syncthreads();

    const float* in = s_in + slot * 33;

    float nss = sb_nss[o], nsv = sb_nsv[o];
#pragma unroll
    for (int c = 0; c < 4; ++c) {
        float x = in[c];
        nss += x * sW_nss[c * 16 + o];
        nsv += x * sW_nsv[c * 16 + o];
    }
    float nvv0 = 0.f, nvv1 = 0.f, nvv2 = 0.f;
#pragma unroll
    for (int c = 0; c < 3; ++c) {
        float w = sW_nvv[c * 16 + o];
        nvv0 += in[4 + c * 3 + 0] * w;
        nvv1 += in[4 + c * 3 + 1] * w;
        nvv2 += in[4 + c * 3 + 2] * w;
    }
    float cc = in[19];
    float es = cc * sb_ess[o], ev = cc * sb_esv[o];
#pragma unroll
    for (int c = 0; c < 6; ++c) {
        float a = in[13 + c];
        es += a * sW_ess[c * 16 + o];
        ev += a * sW_esv[c * 16 + o];
    }
    float EV0 = 0.f, EV1 = 0.f, EV2 = 0.f;
#pragma unroll
    for (int c = 0; c < 3; ++c) {
        float w = sW_evv[c * 16 + o];
        EV0 += in[20 + c * 3 + 0] * w;
        EV1 += in[20 + c * 3 + 1] * w;
        EV2 += in[20 + c * 3 + 2] * w;
    }

    float asca = nss * es;
    float av0 = nvv0 * ev + nsv * EV0;
    float av1 = nvv1 * ev + nsv * EV1;
    float av2 = nvv2 * ev + nsv * EV2;
    s_avec[slot * 49 + o * 3 + 0] = av0;
    s_avec[slot * 49 + o * 3 + 1] = av1;
    s_avec[slot * 49 + o * 3 + 2] = av2;
    s_cat[slot * 33 + 16 + o] = asca;
    __syncthreads();

    float vi0 = 0.f, vi1 = 0.f, vi2 = 0.f;
#pragma unroll
    for (int c = 0; c < 16; ++c) {
        float w = sW_lv[c * 16 + o];
        const float* a = &s_avec[slot * 49 + c * 3];
        vi0 += a[0] * w; vi1 += a[1] * w; vi2 += a[2] * w;
    }
    float vnorm = sqrtf(vi0 * vi0 + vi1 * vi1 + vi2 * vi2);
    s_vint[slot * 49 + o * 3 + 0] = vi0;
    s_vint[slot * 49 + o * 3 + 1] = vi1;
    s_vint[slot * 49 + o * 3 + 2] = vi2;
    s_cat[slot * 33 + o] = vnorm;
    __syncthreads();

    float osca = 0.f;
#pragma unroll
    for (int c = 0; c < 32; ++c)
        osca += s_cat[slot * 33 + c] * sW_ls[c * 16 + o];
    float ov0 = 0.f, ov1 = 0.f, ov2 = 0.f;
#pragma unroll
    for (int c = 0; c < 16; ++c) {
        float w = sW_lv2[c * 16 + o];
        const float* a = &s_vint[slot * 49 + c * 3];
        ov0 += a[0] * w; ov1 += a[1] * w; ov2 += a[2] * w;
    }
    s_osca[slot * 17 + o] = osca;
    __syncthreads();

    float g = sb_gate[o];
#pragma unroll
    for (int c = 0; c < 16; ++c)
        g += s_osca[slot * 17 + c] * sW_gate[c * 16 + o];
    g = 1.0f / (1.0f + __expf(-g));
    ov0 *= g; ov1 *= g; ov2 *= g;
    s_ovec[slot * 49 + o * 3 + 0] = ov0;
    s_ovec[slot * 49 + o * 3 + 1] = ov1;
    s_ovec[slot * 49 + o * 3 + 2] = ov2;
    __syncthreads();

    float dv0 = 0.f, dv1 = 0.f, dv2 = 0.f;
#pragma unroll
    for (int c = 0; c < 16; ++c) {
        float w = sW_dir[c * 16 + o];
        const float* a = &s_ovec[slot * 49 + c * 3];
        dv0 += a[0] * w; dv1 += a[1] * w; dv2 += a[2] * w;
    }
    float dot = ov0 * dv0 + ov1 * dv1 + ov2 * dv2;
    if (dot < 0.0f) {
        float dn = dv0 * dv0 + dv1 * dv1 + dv2 * dv2;
        float f = 0.8f * dot / (dn + 1e-6f);
        ov0 -= f * dv0; ov1 -= f * dv1; ov2 -= f * dv2;
    }

    if (valid) {
        float so = (osca >= 0.0f) ? osca : 0.01f * osca;
        out[(size_t)n * 16 + o] = so;
        size_t vb = (size_t)N * 16 + (size_t)n * 48 + (size_t)o * 3;
        out[vb + 0] = ov0;
        out[vb + 1] = ov1;
        out[vb + 2] = ov2;
    }
}

extern "C" void kernel_launch(void* const* d_in, const int* in_sizes, int n_in,
                              void* d_out, int out_size, void* d_ws, size_t ws_size,
                              hipStream_t stream)
{
    const float* node_sca = (const float*)d_in[0];
    const float* node_vec = (const float*)d_in[1];
    const float* edge_sca = (const float*)d_in[2];
    const float* edge_vec = (const float*)d_in[3];
    const float* gds      = (const float*)d_in[4];
    const int*   eidx     = (const int*)d_in[5];

    const int N = in_sizes[0] / 4;   // node_sca is [N,4]
    const int E = in_sizes[4];       // gds_dist is [E]

    // ---- layout: [count N][gslot 16][aggr N*16][bucket N*KID][packed C*16]
    int*   countp = (int*)d_ws;
    int*   gslot  = countp + N;
    float* aggrp  = (float*)(countp + N + 16);
    int*   bucket = (int*)(aggrp + (size_t)N * 16);
    float* packed = (float*)(bucket + (size_t)N * KID);
    size_t zero_bytes = (size_t)N * 4 + 64 + (size_t)N * 64;   // count+gslot+aggr
    size_t fixed      = zero_bytes + (size_t)N * KID * 4;

    long long C = 0;
    if (ws_size > fixed)
        C = (long long)((ws_size - fixed) / 64);   // packed rows of 64B
    if (C > E) C = E;

    if (C >= (long long)((double)E * 0.85)) {
        hipMemsetAsync(countp, 0, zero_bytes, stream);
        pack_compact<<<(E + 255) / 256, 256, 0, stream>>>(
            gds, eidx, edge_sca, edge_vec,
            countp, gslot, bucket, packed, aggrp, E, (int)C);
        node_fused<<<(N + 15) / 16, 256, 0, stream>>>(
            node_sca, node_vec, edge_sca, edge_vec, gds,
            countp, bucket, packed, aggrp,
            (const float*)d_in[6],  (const float*)d_in[7],
            (const float*)d_in[8],  (const float*)d_in[9],
            (const float*)d_in[10], (const float*)d_in[11],
            (const float*)d_in[12], (const float*)d_in[13],
            (const float*)d_in[14], (const float*)d_in[15],
            (const float*)d_in[16], (const float*)d_in[17],
            (const float*)d_in[18],
            (const float*)d_in[19], (const float*)d_in[20],
            (const float*)d_in[21],
            (float*)d_out, N, 6);
        return;
    }

    if (ws_size >= fixed) {
        hipMemsetAsync(countp, 0, zero_bytes, stream);
        fill_ids<<<(E + 255) / 256, 256, 0, stream>>>(
            gds, eidx, edge_sca, edge_vec, countp, bucket, aggrp, E);
        node_fused<<<(N + 15) / 16, 256, 0, stream>>>(
            node_sca, node_vec, edge_sca, edge_vec, gds,
            countp, bucket, packed, aggrp,
            (const float*)d_in[6],  (const float*)d_in[7],
            (const float*)d_in[8],  (const float*)d_in[9],
            (const float*)d_in[10], (const float*)d_in[11],
            (const float*)d_in[12], (const float*)d_in[13],
            (const float*)d_in[14], (const float*)d_in[15],
            (const float*)d_in[16], (const float*)d_in[17],
            (const float*)d_in[18],
            (const float*)d_in[19], (const float*)d_in[20],
            (const float*)d_in[21],
            (float*)d_out, N, 4);
        return;
    }

    // fallback: fp32 atomic aggregation
    float* aggr0 = (float*)d_ws;
    hipMemsetAsync(aggr0, 0, (size_t)N * 64, stream);
    edge_aggregate<<<(E + 255) / 256, 256, 0, stream>>>(
        edge_sca, edge_vec, gds, eidx, aggr0, E);
    node_fused<<<(N + 15) / 16, 256, 0, stream>>>(
        node_sca, node_vec, edge_sca, edge_vec, gds,
        (const int*)d_ws, (const int*)d_ws, (const float*)d_ws, aggr0,
        (const float*)d_in[6],  (const float*)d_in[7],
        (const float*)d_in[8],  (const float*)d_in[9],
        (const float*)d_in[10], (const float*)d_in[11],
        (const float*)d_in[12], (const float*)d_in[13],
        (const float*)d_in[14], (const float*)d_in[15],
        (const float*)d_in[16], (const float*)d_in[17],
        (const float*)d_in[18],
        (const float*)d_in[19], (const float*)d_in[20],
        (const float*)d_in[21],
        (float*)d_out, N, 0);
}

// Round 5
// 412.098 us; speedup vs baseline: 1.2990x; 1.2990x over previous
//
#include <hip/hip_runtime.h>
#include <math.h>

// Problem constants (match reference)
#define CUTOFF_F 10.0f
#define PI_OVER_CUTOFF 0.31415926535897931f  // pi/10
#define NPB    98   // nodes per coarse bucket
#define NTILES 7    // ceil(NPB/16) node-pipeline tiles per block

// ===========================================================================
// Pass 1: stream edges; append (src, 16 c-folded fp32 feats) to the coarse
// bucket of src. ~1021 append streams -> hot tail lines, every 64B record is
// a full aligned sector, 64 independent chains per wave. The ONLY per-edge
// random traffic is the bucket-counter atomic (1021 padded counters, L2-hot).
// Overflow (slot >= cap) -> fp32 atomics into aggr_ovf (rare/never).
// ===========================================================================
__global__ __launch_bounds__(256) void bucket_append(
    const float* __restrict__ gds,
    const int* __restrict__ eidx,
    const float* __restrict__ edge_sca,
    const float* __restrict__ edge_vec,
    int* __restrict__ bcnt,       // [NBk*16] zeroed (stride-16 padded counters)
    int* __restrict__ flag,       // [16] zeroed; flag[0]=1 on any overflow
    float* __restrict__ aggr_ovf, // [N*16] zeroed overflow accumulator
    int* __restrict__ ids,        // [NBk*cap] src per record
    float* __restrict__ feats,    // [NBk*cap*16] c-folded features
    int E, int cap)
{
    int e = blockIdx.x * 256 + threadIdx.x;
    if (e >= E) return;

    float d = gds[e];
    if (d < 0.0f || d > CUTOFF_F) return;   // coeff==0 -> drop (~17%)

    float c = 0.5f * (__cosf(d * PI_OVER_CUTOFF) + 1.0f);
    int src = eidx[e];
    const float* es = edge_sca + (size_t)e * 6;
    const float* ev = edge_vec + (size_t)e * 9;

    float f[16];
#pragma unroll
    for (int i = 0; i < 6; ++i) f[i] = c * es[i];
    f[6] = c;
#pragma unroll
    for (int i = 0; i < 9; ++i) f[7 + i] = c * ev[i];

    int b = src / NPB;
    int slot = atomicAdd(&bcnt[b * 16], 1);

    if (slot < cap) {
        size_t r = (size_t)b * cap + slot;
        ids[r] = src;
        float4* pr = (float4*)(feats + r * 16);
        pr[0] = make_float4(f[0],  f[1],  f[2],  f[3]);
        pr[1] = make_float4(f[4],  f[5],  f[6],  f[7]);
        pr[2] = make_float4(f[8],  f[9],  f[10], f[11]);
        pr[3] = make_float4(f[12], f[13], f[14], f[15]);
    } else {
        flag[0] = 1;
        float* bb = aggr_ovf + (size_t)src * 16;
#pragma unroll
        for (int i = 0; i < 16; ++i) atomicAdd(bb + i, f[i]);
    }
}

// ===========================================================================
// Fallback: pure fp32 atomic aggregation into aggr_ovf (tiny workspace)
// ===========================================================================
__global__ __launch_bounds__(256) void edge_aggregate(
    const float* __restrict__ edge_sca, const float* __restrict__ edge_vec,
    const float* __restrict__ gds, const int* __restrict__ eidx,
    float* __restrict__ aggr, int E)
{
    int e = blockIdx.x * blockDim.x + threadIdx.x;
    if (e >= E) return;
    int src = eidx[e];
    float d = gds[e];
    float coeff = 0.0f;
    if (d >= 0.0f && d <= CUTOFF_F)
        coeff = 0.5f * (__cosf(d * PI_OVER_CUTOFF) + 1.0f);
    float* base = aggr + (size_t)src * 16;
    const float* es = edge_sca + (size_t)e * 6;
    const float* ev = edge_vec + (size_t)e * 9;
#pragma unroll
    for (int c = 0; c < 6; ++c) atomicAdd(base + c, coeff * es[c]);
    atomicAdd(base + 6, coeff);
#pragma unroll
    for (int k = 0; k < 9; ++k) atomicAdd(base + 7 + k, coeff * ev[k]);
}

// ===========================================================================
// Pass 2 (fused): one block per coarse bucket. Stream the bucket's records
// sequentially, reduce into LDS via ds_add_f32, fold overflow accumulator if
// flagged, then run the full node pipeline for the bucket's 98 nodes
// (7 tiles x 16 nodes, 16 lanes per node).
// forceOvf=1: skip streaming (cap may be 0), aggregate purely from aggr_ovf.
// ===========================================================================
__global__ __launch_bounds__(256) void bucket_reduce_node(
    const float* __restrict__ node_sca,
    const float* __restrict__ node_vec,
    const int* __restrict__ bcnt,
    const int* __restrict__ flag,
    const float* __restrict__ aggr_ovf,
    const int* __restrict__ ids,
    const float* __restrict__ feats,
    const float* __restrict__ W_nss, const float* __restrict__ b_nss,
    const float* __restrict__ W_ess, const float* __restrict__ b_ess,
    const float* __restrict__ W_nsv, const float* __restrict__ b_nsv,
    const float* __restrict__ W_esv, const float* __restrict__ b_esv,
    const float* __restrict__ W_nvv, const float* __restrict__ W_evv,
    const float* __restrict__ W_lv,  const float* __restrict__ W_lv2,
    const float* __restrict__ W_ls,
    const float* __restrict__ W_gate, const float* __restrict__ b_gate,
    const float* __restrict__ W_dir,
    float* __restrict__ out,
    int N, int cap, int forceOvf)
{
    // ---- weights in LDS ----
    __shared__ float sW_nss[64],  sb_nss[16];
    __shared__ float sW_ess[96],  sb_ess[16];
    __shared__ float sW_nsv[64],  sb_nsv[16];
    __shared__ float sW_esv[96],  sb_esv[16];
    __shared__ float sW_nvv[48],  sW_evv[48];
    __shared__ float sW_lv[256],  sW_lv2[256];
    __shared__ float sW_ls[512];
    __shared__ float sW_gate[256], sb_gate[16];
    __shared__ float sW_dir[256];

    // ---- bucket accumulator (stride 17: no bank conflicts) ----
    __shared__ float s_aggr[NPB * 17];

    // ---- per-tile scratch (16 nodes, odd strides) ----
    __shared__ float s_in  [16 * 33];
    __shared__ float s_avec[16 * 49];
    __shared__ float s_cat [16 * 33];
    __shared__ float s_vint[16 * 49];
    __shared__ float s_osca[16 * 17];
    __shared__ float s_ovec[16 * 49];

    const int t = threadIdx.x;
    {
        for (int i = t; i < 64;  i += 256) { sW_nss[i] = W_nss[i]; sW_nsv[i] = W_nsv[i]; }
        for (int i = t; i < 96;  i += 256) { sW_ess[i] = W_ess[i]; sW_esv[i] = W_esv[i]; }
        for (int i = t; i < 48;  i += 256) { sW_nvv[i] = W_nvv[i]; sW_evv[i] = W_evv[i]; }
        for (int i = t; i < 256; i += 256) {
            sW_lv[i]   = W_lv[i];
            sW_lv2[i]  = W_lv2[i];
            sW_gate[i] = W_gate[i];
            sW_dir[i]  = W_dir[i];
        }
        for (int i = t; i < 512; i += 256) sW_ls[i] = W_ls[i];
        if (t < 16) {
            sb_nss[t]  = b_nss[t];
            sb_ess[t]  = b_ess[t];
            sb_nsv[t]  = b_nsv[t];
            sb_esv[t]  = b_esv[t];
            sb_gate[t] = b_gate[t];
        }
    }
    for (int i = t; i < NPB * 17; i += 256) s_aggr[i] = 0.0f;
    __syncthreads();

    const int b     = blockIdx.x;
    const int node0 = b * NPB;
    const int g     = t >> 4;    // group = record lane / node slot
    const int o     = t & 15;    // feature lane

    // ---- stream bucket records -> LDS reduction ----
    if (!forceOvf) {
        int cnt = bcnt[b * 16];
        if (cnt > cap) cnt = cap;
        size_t rb = (size_t)b * cap;
        for (int r = g; r < cnt; r += 16) {
            int src = ids[rb + r];                       // 16-lane broadcast
            float v = feats[(rb + r) * 16 + o];          // coalesced 1KB/iter
            atomicAdd(&s_aggr[(src - node0) * 17 + o], v);   // ds_add_f32
        }
    }
    __syncthreads();

    // ---- fold global overflow accumulator (only if any overflow happened) ----
    int useOvf = forceOvf | flag[0];
    if (useOvf) {
        for (int idx = t; idx < NPB * 16; idx += 256) {
            int nn = idx >> 4, oo = idx & 15;
            int n = node0 + nn;
            if (n < N) s_aggr[nn * 17 + oo] += aggr_ovf[(size_t)n * 16 + oo];
        }
    }
    __syncthreads();

    // ---- node pipeline: NTILES tiles of 16 nodes ----
    for (int tile = 0; tile < NTILES; ++tile) {
        const int slotn = tile * 16 + g;          // node index within bucket
        const int n     = node0 + slotn;
        const bool valid = (slotn < NPB) && (n < N);
        const int slot = g;

        if (valid) {
            if (o < 4) s_in[slot * 33 + o]     = node_sca[(size_t)n * 4 + o];
            if (o < 9) s_in[slot * 33 + 4 + o] = node_vec[(size_t)n * 9 + o];
            s_in[slot * 33 + 13 + o] = s_aggr[slotn * 17 + o];
        }
        __syncthreads();

        const float* in = s_in + slot * 33;

        float nss = sb_nss[o], nsv = sb_nsv[o];
#pragma unroll
        for (int c = 0; c < 4; ++c) {
            float x = in[c];
            nss += x * sW_nss[c * 16 + o];
            nsv += x * sW_nsv[c * 16 + o];
        }
        float nvv0 = 0.f, nvv1 = 0.f, nvv2 = 0.f;
#pragma unroll
        for (int c = 0; c < 3; ++c) {
            float w = sW_nvv[c * 16 + o];
            nvv0 += in[4 + c * 3 + 0] * w;
            nvv1 += in[4 + c * 3 + 1] * w;
            nvv2 += in[4 + c * 3 + 2] * w;
        }
        float cc = in[19];
        float es = cc * sb_ess[o], ev = cc * sb_esv[o];
#pragma unroll
        for (int c = 0; c < 6; ++c) {
            float a = in[13 + c];
            es += a * sW_ess[c * 16 + o];
            ev += a * sW_esv[c * 16 + o];
        }
        float EV0 = 0.f, EV1 = 0.f, EV2 = 0.f;
#pragma unroll
        for (int c = 0; c < 3; ++c) {
            float w = sW_evv[c * 16 + o];
            EV0 += in[20 + c * 3 + 0] * w;
            EV1 += in[20 + c * 3 + 1] * w;
            EV2 += in[20 + c * 3 + 2] * w;
        }

        float asca = nss * es;
        float av0 = nvv0 * ev + nsv * EV0;
        float av1 = nvv1 * ev + nsv * EV1;
        float av2 = nvv2 * ev + nsv * EV2;
        s_avec[slot * 49 + o * 3 + 0] = av0;
        s_avec[slot * 49 + o * 3 + 1] = av1;
        s_avec[slot * 49 + o * 3 + 2] = av2;
        s_cat[slot * 33 + 16 + o] = asca;
        __syncthreads();

        float vi0 = 0.f, vi1 = 0.f, vi2 = 0.f;
#pragma unroll
        for (int c = 0; c < 16; ++c) {
            float w = sW_lv[c * 16 + o];
            const float* a = &s_avec[slot * 49 + c * 3];
            vi0 += a[0] * w; vi1 += a[1] * w; vi2 += a[2] * w;
        }
        float vnorm = sqrtf(vi0 * vi0 + vi1 * vi1 + vi2 * vi2);
        s_vint[slot * 49 + o * 3 + 0] = vi0;
        s_vint[slot * 49 + o * 3 + 1] = vi1;
        s_vint[slot * 49 + o * 3 + 2] = vi2;
        s_cat[slot * 33 + o] = vnorm;
        __syncthreads();

        float osca = 0.f;
#pragma unroll
        for (int c = 0; c < 32; ++c)
            osca += s_cat[slot * 33 + c] * sW_ls[c * 16 + o];
        float ov0 = 0.f, ov1 = 0.f, ov2 = 0.f;
#pragma unroll
        for (int c = 0; c < 16; ++c) {
            float w = sW_lv2[c * 16 + o];
            const float* a = &s_vint[slot * 49 + c * 3];
            ov0 += a[0] * w; ov1 += a[1] * w; ov2 += a[2] * w;
        }
        s_osca[slot * 17 + o] = osca;
        __syncthreads();

        float gg = sb_gate[o];
#pragma unroll
        for (int c = 0; c < 16; ++c)
            gg += s_osca[slot * 17 + c] * sW_gate[c * 16 + o];
        gg = 1.0f / (1.0f + __expf(-gg));
        ov0 *= gg; ov1 *= gg; ov2 *= gg;
        s_ovec[slot * 49 + o * 3 + 0] = ov0;
        s_ovec[slot * 49 + o * 3 + 1] = ov1;
        s_ovec[slot * 49 + o * 3 + 2] = ov2;
        __syncthreads();

        float dv0 = 0.f, dv1 = 0.f, dv2 = 0.f;
#pragma unroll
        for (int c = 0; c < 16; ++c) {
            float w = sW_dir[c * 16 + o];
            const float* a = &s_ovec[slot * 49 + c * 3];
            dv0 += a[0] * w; dv1 += a[1] * w; dv2 += a[2] * w;
        }
        float dot = ov0 * dv0 + ov1 * dv1 + ov2 * dv2;
        if (dot < 0.0f) {
            float dn = dv0 * dv0 + dv1 * dv1 + dv2 * dv2;
            float fr = 0.8f * dot / (dn + 1e-6f);
            ov0 -= fr * dv0; ov1 -= fr * dv1; ov2 -= fr * dv2;
        }

        if (valid) {
            float so = (osca >= 0.0f) ? osca : 0.01f * osca;
            out[(size_t)n * 16 + o] = so;
            size_t vb = (size_t)N * 16 + (size_t)n * 48 + (size_t)o * 3;
            out[vb + 0] = ov0;
            out[vb + 1] = ov1;
            out[vb + 2] = ov2;
        }
        __syncthreads();   // scratch reuse across tiles
    }
}

extern "C" void kernel_launch(void* const* d_in, const int* in_sizes, int n_in,
                              void* d_out, int out_size, void* d_ws, size_t ws_size,
                              hipStream_t stream)
{
    const float* node_sca = (const float*)d_in[0];
    const float* node_vec = (const float*)d_in[1];
    const float* edge_sca = (const float*)d_in[2];
    const float* edge_vec = (const float*)d_in[3];
    const float* gds      = (const float*)d_in[4];
    const int*   eidx     = (const int*)d_in[5];

    const int N = in_sizes[0] / 4;   // node_sca is [N,4]
    const int E = in_sizes[4];       // gds_dist is [E]
    const int NBk = (N + NPB - 1) / NPB;   // coarse buckets (1021 @ N=100K)

    // ---- layout: [bcnt NBk*16][flag 16][aggr_ovf N*16][ids NBk*cap][feats]
    int*   bcnt     = (int*)d_ws;
    int*   flag     = bcnt + (size_t)NBk * 16;
    float* aggr_ovf = (float*)(flag + 16);
    int*   ids      = (int*)(aggr_ovf + (size_t)N * 16);
    size_t zero_bytes = ((size_t)NBk * 16 + 16) * 4 + (size_t)N * 64;

    long long cap = 0;
    if (ws_size > zero_bytes + 64)
        cap = (long long)((ws_size - zero_bytes - 64) / ((size_t)NBk * 68));
    {   // no need for more than ~2x mean bucket load
        long long capMax = 2LL * E / (NBk > 0 ? NBk : 1) + 64;
        if (cap > capMax) cap = capMax;
    }
    size_t ids_bytes = (((size_t)NBk * (size_t)cap * 4) + 63) & ~(size_t)63;
    float* feats = (float*)((char*)ids + ids_bytes);

    if (cap >= 1100 || (cap >= 256 && (long long)E <= cap * NBk)) {
        hipMemsetAsync(bcnt, 0, zero_bytes, stream);
        bucket_append<<<(E + 255) / 256, 256, 0, stream>>>(
            gds, eidx, edge_sca, edge_vec,
            bcnt, flag, aggr_ovf, ids, feats, E, (int)cap);
        bucket_reduce_node<<<NBk, 256, 0, stream>>>(
            node_sca, node_vec, bcnt, flag, aggr_ovf, ids, feats,
            (const float*)d_in[6],  (const float*)d_in[7],
            (const float*)d_in[8],  (const float*)d_in[9],
            (const float*)d_in[10], (const float*)d_in[11],
            (const float*)d_in[12], (const float*)d_in[13],
            (const float*)d_in[14], (const float*)d_in[15],
            (const float*)d_in[16], (const float*)d_in[17],
            (const float*)d_in[18],
            (const float*)d_in[19], (const float*)d_in[20],
            (const float*)d_in[21],
            (float*)d_out, N, (int)cap, 0);
        return;
    }

    // ---- fallback: global fp32 atomic aggregation, then fused node pass ----
    size_t zb = zero_bytes;
    if (zb > ws_size) zb = ws_size;   // hardening: never memset past workspace
    hipMemsetAsync(bcnt, 0, zb, stream);
    edge_aggregate<<<(E + 255) / 256, 256, 0, stream>>>(
        edge_sca, edge_vec, gds, eidx, aggr_ovf, E);
    bucket_reduce_node<<<NBk, 256, 0, stream>>>(
        node_sca, node_vec, bcnt, flag, aggr_ovf, ids, feats,
        (const float*)d_in[6],  (const float*)d_in[7],
        (const float*)d_in[8],  (const float*)d_in[9],
        (const float*)d_in[10], (const float*)d_in[11],
        (const float*)d_in[12], (const float*)d_in[13],
        (const float*)d_in[14], (const float*)d_in[15],
        (const float*)d_in[16], (const float*)d_in[17],
        (const float*)d_in[18],
        (const float*)d_in[19], (const float*)d_in[20],
        (const float*)d_in[21],
        (float*)d_out, N, 0, 1);
}